// Round 2
// baseline (430.151 us; speedup 1.0000x reference)
//
#include <hip/hip_runtime.h>

#define HW 3136
#define NB 32
#define NC 128

// LDS arena: Xs (32x128 = 4096 floats) for the cov phase, then reused as
// double-buffered panel storage: buf k at 2112*k = { Rb[8][132], Rp[8][132] }.
// Stride 132 floats = 528 B keeps every row 16B-aligned (528 = 33*16).

__global__ __launch_bounds__(256, 4)
void mvg_kernel(const float* __restrict__ emb, float* __restrict__ out) {
  const int pos = blockIdx.x;
  const int t = threadIdx.x;

  __shared__ __align__(16) float arena[4224];
  __shared__ float ms[NC];

  float* Xs = arena;

  // ---- gather the (B, C) slice for this position ----
  #pragma unroll
  for (int m = 0; m < 16; ++m) {
    const int idx = t + 256 * m;
    const int b = idx >> 7;
    const int c = idx & (NC - 1);
    Xs[idx] = emb[(size_t)b * ((size_t)NC * HW) + (size_t)c * HW + pos];
  }
  __syncthreads();

  // ---- mean over batch, write mean output ----
  if (t < NC) {
    float s = 0.f;
    #pragma unroll
    for (int b = 0; b < NB; ++b) s += Xs[b * NC + t];
    const float m = s * (1.0f / NB);
    ms[t] = m;
    out[(size_t)t * HW + pos] = m;
  }
  __syncthreads();

  // ---- center in LDS ----
  #pragma unroll
  for (int m = 0; m < 16; ++m) {
    const int idx = t + 256 * m;
    Xs[idx] -= ms[idx & (NC - 1)];
  }
  __syncthreads();

  // ---- per-thread 8x8 tile: rows [i0,i0+8), cols [c0,c0+8) ----
  const int i0 = (t >> 4) << 3;
  const int c0 = (t & 15) << 3;

  float4 a0[8], a1[8];
  #pragma unroll
  for (int r = 0; r < 8; ++r) {
    a0[r] = make_float4(0.f, 0.f, 0.f, 0.f);
    a1[r] = make_float4(0.f, 0.f, 0.f, 0.f);
  }

  // ---- covariance accumulate ----
  for (int b = 0; b < NB; ++b) {
    const float* xr = &Xs[b * NC];
    const float4 rv0 = *(const float4*)&xr[c0];
    const float4 rv1 = *(const float4*)&xr[c0 + 4];
    const float4 cv0 = *(const float4*)&xr[i0];
    const float4 cv1 = *(const float4*)&xr[i0 + 4];
    const float cr[8] = {cv0.x, cv0.y, cv0.z, cv0.w, cv1.x, cv1.y, cv1.z, cv1.w};
    #pragma unroll
    for (int r = 0; r < 8; ++r) {
      a0[r].x = fmaf(cr[r], rv0.x, a0[r].x);
      a0[r].y = fmaf(cr[r], rv0.y, a0[r].y);
      a0[r].z = fmaf(cr[r], rv0.z, a0[r].z);
      a0[r].w = fmaf(cr[r], rv0.w, a0[r].w);
      a1[r].x = fmaf(cr[r], rv1.x, a1[r].x);
      a1[r].y = fmaf(cr[r], rv1.y, a1[r].y);
      a1[r].z = fmaf(cr[r], rv1.z, a1[r].z);
      a1[r].w = fmaf(cr[r], rv1.w, a1[r].w);
    }
  }

  // ---- scale by 1/(B-1), add (REG_DIAG + REG_EPS) on the diagonal ----
  {
    const float s31 = 1.0f / (float)(NB - 1);
    const float RD = 0.01f + 1e-5f;
    #pragma unroll
    for (int r = 0; r < 8; ++r) {
      const int gr = i0 + r;
      a0[r].x = a0[r].x * s31 + ((gr == c0 + 0) ? RD : 0.f);
      a0[r].y = a0[r].y * s31 + ((gr == c0 + 1) ? RD : 0.f);
      a0[r].z = a0[r].z * s31 + ((gr == c0 + 2) ? RD : 0.f);
      a0[r].w = a0[r].w * s31 + ((gr == c0 + 3) ? RD : 0.f);
      a1[r].x = a1[r].x * s31 + ((gr == c0 + 4) ? RD : 0.f);
      a1[r].y = a1[r].y * s31 + ((gr == c0 + 5) ? RD : 0.f);
      a1[r].z = a1[r].z * s31 + ((gr == c0 + 6) ? RD : 0.f);
      a1[r].w = a1[r].w * s31 + ((gr == c0 + 7) ? RD : 0.f);
    }
  }
  __syncthreads();   // arena reuse: all Xs reads done before panel writes

  // In-register panel sweep over pivot p (within the 16 owner lanes, shfl width 16).
  // cc[i] = pivot-column values (from lane s, which owns the diagonal block cols).
  #define PANEL_PIVOT(p, REG, COMP) {                                        \
    float cc[8];                                                             \
    _Pragma("unroll")                                                        \
    for (int i = 0; i < 8; ++i) cc[i] = __shfl(REG[i].COMP, s, 16);          \
    const float rd = __builtin_amdgcn_rcpf(cc[p]);                           \
    a0[p].x *= rd; a0[p].y *= rd; a0[p].z *= rd; a0[p].w *= rd;              \
    a1[p].x *= rd; a1[p].y *= rd; a1[p].z *= rd; a1[p].w *= rd;              \
    _Pragma("unroll")                                                        \
    for (int i = 0; i < 8; ++i) if (i != (p)) {                              \
      a0[i].x = fmaf(-cc[i], a0[p].x, a0[i].x);                              \
      a0[i].y = fmaf(-cc[i], a0[p].y, a0[i].y);                              \
      a0[i].z = fmaf(-cc[i], a0[p].z, a0[i].z);                              \
      a0[i].w = fmaf(-cc[i], a0[p].w, a0[i].w);                              \
      a1[i].x = fmaf(-cc[i], a1[p].x, a1[i].x);                              \
      a1[i].y = fmaf(-cc[i], a1[p].y, a1[i].y);                              \
      a1[i].z = fmaf(-cc[i], a1[p].z, a1[i].z);                              \
      a1[i].w = fmaf(-cc[i], a1[p].w, a1[i].w);                              \
    }                                                                        \
    if (dg) {                                                                \
      REG[p].COMP = -rd;                                                     \
      _Pragma("unroll")                                                      \
      for (int i = 0; i < 8; ++i) if (i != (p)) REG[i].COMP = cc[i] * rd;    \
    }                                                                        \
  }

  // Rank-8 trailing update (non-panel-row tiles). Panel-col tiles get R'^T assigned.
  #define R8_STEP(p, REG, COMP) {                                            \
    const float4 rp0 = *(const float4*)&Rp_[(p) * 132 + i0];                 \
    const float4 rp1 = *(const float4*)&Rp_[(p) * 132 + i0 + 4];             \
    if (colTile) {                                                           \
      REG[0].COMP = rp0.x; REG[1].COMP = rp0.y;                              \
      REG[2].COMP = rp0.z; REG[3].COMP = rp0.w;                              \
      REG[4].COMP = rp1.x; REG[5].COMP = rp1.y;                              \
      REG[6].COMP = rp1.z; REG[7].COMP = rp1.w;                              \
    } else {                                                                 \
      const float4 rr0 = *(const float4*)&Rb_[(p) * 132 + c0];               \
      const float4 rr1 = *(const float4*)&Rb_[(p) * 132 + c0 + 4];           \
      const float cr[8] = {rp0.x, rp0.y, rp0.z, rp0.w,                       \
                           rp1.x, rp1.y, rp1.z, rp1.w};                      \
      _Pragma("unroll")                                                      \
      for (int r = 0; r < 8; ++r) {                                          \
        a0[r].x = fmaf(-cr[r], rr0.x, a0[r].x);                              \
        a0[r].y = fmaf(-cr[r], rr0.y, a0[r].y);                              \
        a0[r].z = fmaf(-cr[r], rr0.z, a0[r].z);                              \
        a0[r].w = fmaf(-cr[r], rr0.w, a0[r].w);                              \
        a1[r].x = fmaf(-cr[r], rr1.x, a1[r].x);                              \
        a1[r].y = fmaf(-cr[r], rr1.y, a1[r].y);                              \
        a1[r].z = fmaf(-cr[r], rr1.z, a1[r].z);                              \
        a1[r].w = fmaf(-cr[r], rr1.w, a1[r].w);                              \
      }                                                                      \
    }                                                                        \
  }

  // ---- blocked sweep: 16 block-steps of 8 pivots, ONE barrier each ----
  #pragma unroll 1
  for (int s = 0; s < 16; ++s) {
    float* Rb_ = arena + 2112 * (s & 1);
    float* Rp_ = Rb_ + 1056;
    const int ks = s << 3;

    if ((t >> 4) == s) {           // 16 owner threads (one quarter-wave)
      const int l = t & 15;
      const bool dg = (l == s);
      // publish R_orig
      #pragma unroll
      for (int i = 0; i < 8; ++i) {
        *(float4*)&Rb_[i * 132 + 8 * l] = a0[i];
        *(float4*)&Rb_[i * 132 + 8 * l + 4] = a1[i];
      }
      // in-register 8-pivot sweep of the panel
      PANEL_PIVOT(0, a0, x)
      PANEL_PIVOT(1, a0, y)
      PANEL_PIVOT(2, a0, z)
      PANEL_PIVOT(3, a0, w)
      PANEL_PIVOT(4, a1, x)
      PANEL_PIVOT(5, a1, y)
      PANEL_PIVOT(6, a1, z)
      PANEL_PIVOT(7, a1, w)
      // publish R' (= B^{-1} R; B-cols hold -B^{-1}, never read by others)
      #pragma unroll
      for (int i = 0; i < 8; ++i) {
        *(float4*)&Rp_[i * 132 + 8 * l] = a0[i];
        *(float4*)&Rp_[i * 132 + 8 * l + 4] = a1[i];
      }
    }
    __syncthreads();

    const bool colTile = (c0 == ks);
    if (i0 != ks) {
      R8_STEP(0, a0, x)
      R8_STEP(1, a0, y)
      R8_STEP(2, a0, z)
      R8_STEP(3, a0, w)
      R8_STEP(4, a1, x)
      R8_STEP(5, a1, y)
      R8_STEP(6, a1, z)
      R8_STEP(7, a1, w)
    }
  }

  // ---- store inverse: inv = -(swept matrix), uniformly ----
  float* o = out + (size_t)NC * HW + (size_t)pos * (NC * NC);
  #pragma unroll
  for (int r = 0; r < 8; ++r) {
    const int gr = i0 + r;
    float4 w0, w1;
    w0.x = -a0[r].x; w0.y = -a0[r].y; w0.z = -a0[r].z; w0.w = -a0[r].w;
    w1.x = -a1[r].x; w1.y = -a1[r].y; w1.z = -a1[r].z; w1.w = -a1[r].w;
    *(float4*)&o[(size_t)gr * NC + c0] = w0;
    *(float4*)&o[(size_t)gr * NC + c0 + 4] = w1;
  }
}

extern "C" void kernel_launch(void* const* d_in, const int* in_sizes, int n_in,
                              void* d_out, int out_size, void* d_ws, size_t ws_size,
                              hipStream_t stream) {
  const float* emb = (const float*)d_in[0];
  float* out = (float*)d_out;
  mvg_kernel<<<HW, 256, 0, stream>>>(emb, out);
}